// Round 1
// baseline (128.198 us; speedup 1.0000x reference)
//
#include <hip/hip_runtime.h>

// SimpleMHA2D: B=32, S=HW=1024, C=KV=1024, N=16, K=V=64, fp32.
// Pipeline:
//  K1: qk[c][n] = sum_k k_kernel[c][n*64+k]*q[n][k];  qb[n] = sum_k k_bias*q
//  K2: logits[b][n][s] = x[b,s,:] . qk[:,n] + qb[n]        (skinny GEMM)
//  K3: per (b,n): m = max_s, e[b][s][n] = exp(l-m), l_sum
//  K4: wp[b][ch][n][c] = sum_{s in chunk} e[b][s][n]*x[b,s,c]
//  K5: out[b][n][v] = (sum_ch wp . vk[:, n*64+v]) / l_sum + vb[n*64+v]

__device__ __forceinline__ float wave_sum64(float x) {
  // rocPRIM-style DPP reduction; total lands in lane 63. VALU-only (no DS pipe).
  int t;
  t = __builtin_amdgcn_update_dpp(0, __float_as_int(x), 0x111, 0xF, 0xF, true); x += __int_as_float(t); // row_shr:1
  t = __builtin_amdgcn_update_dpp(0, __float_as_int(x), 0x112, 0xF, 0xF, true); x += __int_as_float(t); // row_shr:2
  t = __builtin_amdgcn_update_dpp(0, __float_as_int(x), 0x114, 0xF, 0xF, true); x += __int_as_float(t); // row_shr:4
  t = __builtin_amdgcn_update_dpp(0, __float_as_int(x), 0x118, 0xF, 0xF, true); x += __int_as_float(t); // row_shr:8
  t = __builtin_amdgcn_update_dpp(0, __float_as_int(x), 0x142, 0xF, 0xF, true); x += __int_as_float(t); // row_bcast:15
  t = __builtin_amdgcn_update_dpp(0, __float_as_int(x), 0x143, 0xF, 0xF, true); x += __int_as_float(t); // row_bcast:31
  return x;
}

// ---------------- K1: fold query into k_kernel ----------------
__global__ __launch_bounds__(256) void k_qk(const float* __restrict__ kk,
                                            const float* __restrict__ q,
                                            const float* __restrict__ kb,
                                            float* __restrict__ qk,
                                            float* __restrict__ qb) {
  const int gid = blockIdx.x * 256 + threadIdx.x;   // 16384 = 1024c * 16n
  const int c = gid >> 4, n = gid & 15;
  float a = 0.f;
#pragma unroll
  for (int k4 = 0; k4 < 64; k4 += 4) {
    const float4 kv = *(const float4*)(kk + (size_t)c * 1024 + n * 64 + k4);
    const float4 qv = *(const float4*)(q + n * 64 + k4);
    a += kv.x * qv.x + kv.y * qv.y + kv.z * qv.z + kv.w * qv.w;
  }
  qk[gid] = a;  // layout [c][n], gid == c*16+n
  if (blockIdx.x == 0 && threadIdx.x < 16) {
    float s = 0.f;
    for (int k = 0; k < 64; k++) s += kb[threadIdx.x * 64 + k] * q[threadIdx.x * 64 + k];
    qb[threadIdx.x] = s;
  }
}

// ---------------- K2: logits_t[b][n][s] = x . qk + qb ----------------
__global__ __launch_bounds__(256) void k_logits(const float* __restrict__ x,
                                                const float* __restrict__ qk,
                                                const float* __restrict__ qb,
                                                float* __restrict__ lg) {
  const int lane = threadIdx.x & 63;
  const int wid  = threadIdx.x >> 6;
  const int group = blockIdx.x * 4 + wid;  // 8192 groups of 4 rows
  const int row0 = group * 4;
  const int b  = row0 >> 10;
  const int s0 = row0 & 1023;

  float acc[4][16];
#pragma unroll
  for (int r = 0; r < 4; r++)
#pragma unroll
    for (int n = 0; n < 16; n++) acc[r][n] = 0.f;

#pragma unroll
  for (int cb = 0; cb < 1024; cb += 256) {
    const int c4 = cb + lane * 4;
    float4 x4[4];
#pragma unroll
    for (int r = 0; r < 4; r++)
      x4[r] = *(const float4*)(x + (size_t)(row0 + r) * 1024 + c4);
#pragma unroll
    for (int j = 0; j < 4; j++) {
      const float* qrow = qk + (size_t)(c4 + j) * 16;
      const float4 q0 = ((const float4*)qrow)[0];
      const float4 q1 = ((const float4*)qrow)[1];
      const float4 q2 = ((const float4*)qrow)[2];
      const float4 q3 = ((const float4*)qrow)[3];
#pragma unroll
      for (int r = 0; r < 4; r++) {
        const float xs = ((const float*)&x4[r])[j];
        acc[r][0]  += xs * q0.x; acc[r][1]  += xs * q0.y; acc[r][2]  += xs * q0.z; acc[r][3]  += xs * q0.w;
        acc[r][4]  += xs * q1.x; acc[r][5]  += xs * q1.y; acc[r][6]  += xs * q1.z; acc[r][7]  += xs * q1.w;
        acc[r][8]  += xs * q2.x; acc[r][9]  += xs * q2.y; acc[r][10] += xs * q2.z; acc[r][11] += xs * q2.w;
        acc[r][12] += xs * q3.x; acc[r][13] += xs * q3.y; acc[r][14] += xs * q3.z; acc[r][15] += xs * q3.w;
      }
    }
  }

#pragma unroll
  for (int r = 0; r < 4; r++)
#pragma unroll
    for (int n = 0; n < 16; n++) acc[r][n] = wave_sum64(acc[r][n]);

  if (lane == 63) {
#pragma unroll
    for (int r = 0; r < 4; r++)
#pragma unroll
      for (int n = 0; n < 16; n++)
        lg[(size_t)(b * 16 + n) * 1024 + s0 + r] = acc[r][n] + qb[n];
  }
}

// ---------------- K3: softmax stats + exp (transposed write) ----------------
__global__ __launch_bounds__(256) void k_softmax(const float* __restrict__ lg,
                                                 float* __restrict__ es,
                                                 float* __restrict__ lsum) {
  const int bi = blockIdx.x;  // b*16+n, 512 blocks
  const int b = bi >> 4, n = bi & 15;
  const int tid = threadIdx.x;
  __shared__ float red[256];

  const float4 lv = *(const float4*)(lg + (size_t)bi * 1024 + tid * 4);
  float lm = fmaxf(fmaxf(lv.x, lv.y), fmaxf(lv.z, lv.w));
  red[tid] = lm; __syncthreads();
  for (int off = 128; off; off >>= 1) {
    if (tid < off) red[tid] = fmaxf(red[tid], red[tid + off]);
    __syncthreads();
  }
  const float m = red[0];
  __syncthreads();

  const float e0 = __expf(lv.x - m), e1 = __expf(lv.y - m);
  const float e2 = __expf(lv.z - m), e3 = __expf(lv.w - m);
  red[tid] = (e0 + e1) + (e2 + e3); __syncthreads();
  for (int off = 128; off; off >>= 1) {
    if (tid < off) red[tid] += red[tid + off];
    __syncthreads();
  }
  if (tid == 0) lsum[bi] = red[0];

  const size_t eb = ((size_t)b * 1024 + tid * 4) * 16 + n;  // es[b][s][n]
  es[eb] = e0; es[eb + 16] = e1; es[eb + 32] = e2; es[eb + 48] = e3;
}

// ---------------- K4: wp[b][ch][n][c] = sum_s e*x ----------------
__global__ __launch_bounds__(1024) void k_wsum(const float* __restrict__ x,
                                               const float* __restrict__ es,
                                               float* __restrict__ wp) {
  const int b = blockIdx.x >> 3, ch = blockIdx.x & 7;  // 256 blocks
  const int tid = threadIdx.x;
  const int lane = tid & 63, wid = tid >> 6;
  const int q = wid & 3, sub = wid >> 2;  // c-quarter, s-subchunk
  __shared__ float wl[16 * 1024];  // 64 KB

  for (int i = tid; i < 16 * 1024; i += 1024) wl[i] = 0.f;
  __syncthreads();

  float acc[16][4];
#pragma unroll
  for (int n = 0; n < 16; n++)
#pragma unroll
    for (int k = 0; k < 4; k++) acc[n][k] = 0.f;

  const int c0 = q * 256 + lane;
  for (int si = 0; si < 32; si++) {
    const int s = ch * 128 + sub * 32 + si;
    const float* xp = x + (size_t)(b * 1024 + s) * 1024;
    const float xk0 = xp[c0], xk1 = xp[c0 + 64], xk2 = xp[c0 + 128], xk3 = xp[c0 + 192];
    float4 e4[4];
    const float4* ep = (const float4*)(es + (size_t)(b * 1024 + s) * 16);
#pragma unroll
    for (int j = 0; j < 4; j++) e4[j] = ep[j];
#pragma unroll
    for (int n = 0; n < 16; n++) {
      const float ev = ((const float*)e4)[n];
      acc[n][0] += ev * xk0; acc[n][1] += ev * xk1;
      acc[n][2] += ev * xk2; acc[n][3] += ev * xk3;
    }
  }

  // phased non-atomic LDS accumulate (deterministic; lane-consecutive -> conflict-free)
  for (int ph = 0; ph < 4; ph++) {
    if (sub == ph) {
#pragma unroll
      for (int n = 0; n < 16; n++) {
        wl[n * 1024 + c0]       += acc[n][0];
        wl[n * 1024 + c0 + 64]  += acc[n][1];
        wl[n * 1024 + c0 + 128] += acc[n][2];
        wl[n * 1024 + c0 + 192] += acc[n][3];
      }
    }
    __syncthreads();
  }

  float* wpb = wp + (size_t)blockIdx.x * 16384;
  for (int i = tid; i < 16384; i += 1024) wpb[i] = wl[i];
}

// ---------------- K5: out = (w . vk)/l + vb ----------------
__global__ __launch_bounds__(256) void k_out(const float* __restrict__ wp,
                                             const float* __restrict__ vk,
                                             const float* __restrict__ vb,
                                             const float* __restrict__ lsum,
                                             float* __restrict__ out) {
  const int bi = blockIdx.x;  // b*16+n, 512 blocks
  const int b = bi >> 4, n = bi & 15;
  const int tid = threadIdx.x;
  __shared__ float wrow[1024];
  __shared__ float red[4][64];

  float4 a4 = {0.f, 0.f, 0.f, 0.f};
#pragma unroll
  for (int ch = 0; ch < 8; ch++) {
    const float4 t = *(const float4*)(wp + ((size_t)(b * 8 + ch) * 16 + n) * 1024 + tid * 4);
    a4.x += t.x; a4.y += t.y; a4.z += t.z; a4.w += t.w;
  }
  *(float4*)&wrow[tid * 4] = a4;
  __syncthreads();

  const int v = tid & 63, cq = tid >> 6;
  float a = 0.f;
  const float* vkc = vk + n * 64 + v;
  for (int ci = 0; ci < 256; ci++) {
    const int c = cq * 256 + ci;
    a += wrow[c] * vkc[(size_t)c * 1024];
  }
  red[cq][v] = a;
  __syncthreads();
  if (tid < 64) {
    const float o = (red[0][tid] + red[1][tid] + red[2][tid] + red[3][tid]) / lsum[bi]
                    + vb[n * 64 + tid];
    out[(size_t)b * 1024 + n * 64 + tid] = o;
  }
}

extern "C" void kernel_launch(void* const* d_in, const int* in_sizes, int n_in,
                              void* d_out, int out_size, void* d_ws, size_t ws_size,
                              hipStream_t stream) {
  const float* x  = (const float*)d_in[0];  // key_value [32,32,32,1024]
  const float* q  = (const float*)d_in[1];  // query [1,1,16,64]
  const float* kk = (const float*)d_in[2];  // k_kernel [1024,1024]
  const float* kb = (const float*)d_in[3];  // k_bias [1024]
  const float* vk = (const float*)d_in[4];  // v_kernel [1024,1024]
  const float* vb = (const float*)d_in[5];  // v_bias [1024]
  float* out = (float*)d_out;               // [32,16,64] fp32

  float* f   = (float*)d_ws;
  float* qk  = f;            // 16384
  float* qb  = f + 16384;    // 16
  float* ls  = f + 16400;    // 512
  float* lg  = f + 32768;    // 524288  logits_t[b][n][s]
  float* es  = f + 557056;   // 524288  e[b][s][n]
  float* wp  = f + 1081344;  // 4194304 wp[b][ch][n][c]   (total ~21.1 MB)

  hipLaunchKernelGGL(k_qk,      dim3(64),   dim3(256),  0, stream, kk, q, kb, qk, qb);
  hipLaunchKernelGGL(k_logits,  dim3(2048), dim3(256),  0, stream, x, qk, qb, lg);
  hipLaunchKernelGGL(k_softmax, dim3(512),  dim3(256),  0, stream, lg, es, ls);
  hipLaunchKernelGGL(k_wsum,    dim3(256),  dim3(1024), 0, stream, x, es, wp);
  hipLaunchKernelGGL(k_out,     dim3(512),  dim3(256),  0, stream, wp, vk, vb, ls, out);
}